// Round 5
// baseline (417.166 us; speedup 1.0000x reference)
//
#include <hip/hip_runtime.h>
#include <stdint.h>

namespace {

constexpr int kBH = 128;
constexpr int kS  = 1024;
constexpr int kD  = 64;
constexpr int kQB = 16;
constexpr float kScale = 0.04419417382415922f;   // 1/sqrt(512)
constexpr float kNegInf = -3.0e38f;

typedef __attribute__((ext_vector_type(8))) short short8;   // 8 bf16
typedef __attribute__((ext_vector_type(4))) short short4v;  // 4 bf16 (8 B)
typedef __attribute__((ext_vector_type(4))) float f32x4;
typedef __attribute__((ext_vector_type(4))) int   i32x4;
typedef __attribute__((ext_vector_type(2))) unsigned int u32x2;

__device__ inline uint16_t f2bf(float f) {       // f32 -> bf16 bits, RNE
    union { float f; uint32_t u; } x; x.f = f;
    uint32_t r = x.u + 0x7fffu + ((x.u >> 16) & 1u);
    return (uint16_t)(r >> 16);
}
__device__ inline float bf2f(uint16_t h) {
    union { uint32_t u; float f; } x; x.u = ((uint32_t)h) << 16;
    return x.f;
}
__device__ inline uint32_t pkbf(float lo, float hi) {
    return (uint32_t)f2bf(lo) | ((uint32_t)f2bf(hi) << 16);
}
__device__ inline float unlo(uint32_t w) { return bf2f((uint16_t)(w & 0xffffu)); }
__device__ inline float unhi(uint32_t w) { return bf2f((uint16_t)(w >> 16)); }

// ---- prep 1: K f32 [bh][k][d] -> bf16 same layout ----
__global__ __launch_bounds__(256)
void conv_k_kernel(const float* __restrict__ K, uint16_t* __restrict__ Kb) {
    const size_t base = ((size_t)blockIdx.x * 256 + threadIdx.x) * 8;
    f32x4 a = __builtin_nontemporal_load((const f32x4*)(K + base));
    f32x4 b = __builtin_nontemporal_load((const f32x4*)(K + base + 4));
    short8 t;
    #pragma unroll
    for (int j = 0; j < 4; ++j) { t[j] = (short)f2bf(a[j]); t[j + 4] = (short)f2bf(b[j]); }
    *(short8*)(Kb + base) = t;
}

// ---- prep 2: V f32 [bh][k][d] -> bf16 transposed Vt [bh][d][k] ----
__global__ __launch_bounds__(256)
void transp_v_kernel(const float* __restrict__ V, uint16_t* __restrict__ Vt) {
    __shared__ float t[64][65];
    const int bh = blockIdx.x >> 4;
    const int kb = blockIdx.x & 15;               // 64-row k block
    const int tid = threadIdx.x;
    const float* vb = V + ((size_t)bh * kS + kb * 64) * kD;
    #pragma unroll
    for (int rep = 0; rep < 4; ++rep) {
        const int k = (tid >> 4) + rep * 16;
        const int d4 = (tid & 15) * 4;
        f32x4 x = __builtin_nontemporal_load((const f32x4*)(vb + (size_t)k * kD + d4));
        #pragma unroll
        for (int j = 0; j < 4; ++j) t[k][d4 + j] = x[j];
    }
    __syncthreads();
    const int d  = tid >> 2;
    const int kq = (tid & 3) * 16;
    short8 o0, o1;
    #pragma unroll
    for (int j = 0; j < 8; ++j) {
        o0[j] = (short)f2bf(t[kq + j][d]);
        o1[j] = (short)f2bf(t[kq + 8 + j][d]);
    }
    uint16_t* orow = Vt + ((size_t)bh * kD + d) * kS + kb * 64 + kq;
    *(short8*)(orow)     = o0;
    *(short8*)(orow + 8) = o1;
}

__global__ __launch_bounds__(512, 8)             // 8 waves/EU -> 4 WG/CU; VGPR<=64
void sdpa_kernel(const float* __restrict__ Q, const uint16_t* __restrict__ Kb,
                 const uint16_t* __restrict__ Vt, const int* __restrict__ M,
                 float* __restrict__ Og, float* __restrict__ Ag) {
    // P: bf16 [16][1024]; column index XOR-swizzled by (row&7)<<3
    __shared__ uint16_t P_lds[kQB * kS];         // 32768 B
    __shared__ float osc[4 * 16 * 16];           //  4096 B (phase-3 k-split combine)
    __shared__ float inv_lds[kQB];               // total 36928 B -> 4 WG/CU

    // XCD swizzle: 1024 consecutive logical WGs (16 bh) per XCD -> Kb/Vt L2-resident
    const int logical = (blockIdx.x & 7) * 1024 + (blockIdx.x >> 3);
    const int bh = logical >> 6;
    const int q0 = (logical & 63) * kQB;

    const int tid  = threadIdx.x;
    const int wave = tid >> 6;
    const int lane = tid & 63;
    const int l16  = lane & 15;
    const int lg   = lane >> 4;

    const float*    qb  = Q  + (size_t)bh * kS * kD;
    const uint16_t* kbb = Kb + (size_t)bh * kS * kD;

    // ---- Q fragment: B-operand B[k=lg*8+j][col=l16 -> q-row] ----
    short8 afr[2];
    #pragma unroll
    for (int ks = 0; ks < 2; ++ks) {
        const float* p = qb + (size_t)(q0 + l16) * kD + ks * 32 + lg * 8;
        f32x4 lo = __builtin_nontemporal_load((const f32x4*)p);
        f32x4 hi = __builtin_nontemporal_load((const f32x4*)(p + 4));
        short8 t;
        #pragma unroll
        for (int j = 0; j < 4; ++j) { t[j] = (short)f2bf(lo[j]); t[j + 4] = (short)f2bf(hi[j]); }
        afr[ks] = t;
    }

    // ---- Phase 1: S^T = K·Q^T -> lane holds 4 consecutive cols of one q-row ----
    const int n0 = wave * 128;
    #pragma unroll 2
    for (int nt = 0; nt < 8; ++nt) {
        const int nb = n0 + nt * 16;
        const uint16_t* krow = kbb + (size_t)(nb + l16) * kD + lg * 8;
        short8 kf0 = *(const short8*)(krow);
        short8 kf1 = *(const short8*)(krow + 32);
        f32x4 acc = {0.f, 0.f, 0.f, 0.f};
        acc = __builtin_amdgcn_mfma_f32_16x16x32_bf16(kf0, afr[0], acc, 0, 0, 0);
        acc = __builtin_amdgcn_mfma_f32_16x16x32_bf16(kf1, afr[1], acc, 0, 0, 0);
        // lane: S[q=q0+l16][n=nb+lg*4+r] -> one packed b64 store
        const int e = l16 * kS + ((nb + lg * 4) ^ ((l16 & 7) << 3));
        u32x2 w; w.x = pkbf(acc[0], acc[1]); w.y = pkbf(acc[2], acc[3]);
        *(u32x2*)(P_lds + e) = w;
    }
    __syncthreads();

    // ---- Phase 2 (single round): mask+scale -> max -> exp -> sum -> stores ----
    {
        const int row = tid >> 5;                 // 16 rows x 32 threads
        const int c0  = (tid & 31) * 4;
        const int swz = (row & 7) << 3;
        const int* mrow = M + ((size_t)bh * kS + q0 + row) * kS;
        uint16_t* prow = P_lds + row * kS;

        i32x4 mk[8];
        #pragma unroll
        for (int i = 0; i < 8; ++i)               // all 8 HBM loads in flight
            mk[i] = __builtin_nontemporal_load((const i32x4*)(mrow + c0 + i * 128));

        u32x2 ps[8];                              // bf16-packed masked-scaled scores
        float mx = kNegInf;
        #pragma unroll
        for (int i = 0; i < 8; ++i) {
            short4v s4 = *(const short4v*)(prow + ((c0 + i * 128) ^ swz));
            float v0 = mk[i].x ? kNegInf : bf2f((uint16_t)s4.x) * kScale;
            float v1 = mk[i].y ? kNegInf : bf2f((uint16_t)s4.y) * kScale;
            float v2 = mk[i].z ? kNegInf : bf2f((uint16_t)s4.z) * kScale;
            float v3 = mk[i].w ? kNegInf : bf2f((uint16_t)s4.w) * kScale;
            ps[i].x = pkbf(v0, v1); ps[i].y = pkbf(v2, v3);
            mx = fmaxf(mx, fmaxf(fmaxf(v0, v1), fmaxf(v2, v3)));
        }
        #pragma unroll
        for (int o = 16; o; o >>= 1) mx = fmaxf(mx, __shfl_xor(mx, o));

        float sum = 0.f;
        #pragma unroll
        for (int i = 0; i < 8; ++i) {
            float p0 = __expf(unlo(ps[i].x) - mx);
            float p1 = __expf(unhi(ps[i].x) - mx);
            float p2 = __expf(unlo(ps[i].y) - mx);
            float p3 = __expf(unhi(ps[i].y) - mx);
            sum += (p0 + p1) + (p2 + p3);
            u32x2 w; w.x = pkbf(p0, p1); w.y = pkbf(p2, p3);
            ps[i] = w;                            // keep packed p in regs
            *(u32x2*)(prow + ((c0 + i * 128) ^ swz)) = w;   // unnormalized p -> LDS
        }
        #pragma unroll
        for (int o = 16; o; o >>= 1) sum += __shfl_xor(sum, o);
        const float inv = 1.0f / sum;
        if ((tid & 31) == 0) inv_lds[row] = inv;

        float* arow = Ag + ((size_t)bh * kS + q0 + row) * kS;
        #pragma unroll
        for (int i = 0; i < 8; ++i) {
            f32x4 a = { unlo(ps[i].x) * inv, unhi(ps[i].x) * inv,
                        unlo(ps[i].y) * inv, unhi(ps[i].y) * inv };
            __builtin_nontemporal_store(a, (f32x4*)(arow + c0 + i * 128));
        }
    }
    __syncthreads();

    // ---- Phase 3: O = P @ V, k-split across wave halves, LDS combine ----
    {
        const int dq = wave & 3;                  // d-slice
        const int kg = wave >> 2;                 // k-half
        const uint16_t* vtrow = Vt + ((size_t)bh * kD + dq * 16 + l16) * kS + kg * 512 + lg * 8;
        const uint16_t* pbase = P_lds + l16 * kS;
        const int aswz = (l16 & 7) << 3;
        f32x4 acc0 = {0.f, 0.f, 0.f, 0.f};
        f32x4 acc1 = {0.f, 0.f, 0.f, 0.f};
        #pragma unroll
        for (int kk = 0; kk < 16; kk += 2) {
            short8 a0 = *(const short8*)(pbase + ((kg * 512 + kk * 32 + lg * 8) ^ aswz));
            short8 b0 = *(const short8*)(vtrow + kk * 32);
            acc0 = __builtin_amdgcn_mfma_f32_16x16x32_bf16(a0, b0, acc0, 0, 0, 0);
            short8 a1 = *(const short8*)(pbase + ((kg * 512 + (kk + 1) * 32 + lg * 8) ^ aswz));
            short8 b1 = *(const short8*)(vtrow + (kk + 1) * 32);
            acc1 = __builtin_amdgcn_mfma_f32_16x16x32_bf16(a1, b1, acc1, 0, 0, 0);
        }
        f32x4 acc = acc0 + acc1;
        if (kg) {                                 // upper k-half -> LDS scratch
            #pragma unroll
            for (int r = 0; r < 4; ++r)
                osc[dq * 256 + (lg * 4 + r) * 16 + l16] = acc[r];
        }
        __syncthreads();
        if (!kg) {                                // combine + epilogue
            f32x4 invv = *(const f32x4*)(inv_lds + lg * 4);
            #pragma unroll
            for (int r = 0; r < 4; ++r) {
                float o = (acc[r] + osc[dq * 256 + (lg * 4 + r) * 16 + l16]) * invv[r];
                __builtin_nontemporal_store(
                    o, Og + ((size_t)bh * kS + q0 + lg * 4 + r) * kD + dq * 16 + l16);
            }
        }
    }
}

} // namespace

extern "C" void kernel_launch(void* const* d_in, const int* in_sizes, int n_in,
                              void* d_out, int out_size, void* d_ws, size_t ws_size,
                              hipStream_t stream) {
    const float* q = (const float*)d_in[0];
    const float* k = (const float*)d_in[1];
    const float* v = (const float*)d_in[2];
    const int*   m = (const int*)d_in[3];
    float* og = (float*)d_out;
    float* ag = og + (size_t)kBH * kS * kD;      // outputs concatenated: O then attn

    uint16_t* kb = (uint16_t*)d_ws;              // 16.78 MB bf16 K
    uint16_t* vt = kb + (size_t)kBH * kS * kD;   // 16.78 MB bf16 V^T [bh][d][k]

    conv_k_kernel<<<dim3(4096), dim3(256), 0, stream>>>(k, kb);
    transp_v_kernel<<<dim3(2048), dim3(256), 0, stream>>>(v, vt);
    sdpa_kernel<<<dim3(kBH * (kS / kQB)), dim3(512), 0, stream>>>(q, kb, vt, m, og, ag);
}